// Round 12
// baseline (130.844 us; speedup 1.0000x reference)
//
#include <hip/hip_runtime.h>
#include <math.h>

// Problem constants (from reference setup_inputs): B=2, S=1024, D=128
#define BB 2
#define SS 1024
#define DD 128

typedef _Float16 v2h __attribute__((ext_vector_type(2)));
typedef _Float16 h16;

// acc += sum_i relu(q_i - k_i) over 8 f16 elements (packed pairs + fdot2).
__device__ __forceinline__ float acc8(float acc, float4 qf, float4 kf)
{
    union U { float4 f; v2h h[4]; };
    U uq; uq.f = qf;
    U uk; uk.f = kf;
    const v2h z = {(h16)0.0f, (h16)0.0f};
#if __has_builtin(__builtin_amdgcn_fdot2)
    const v2h one = {(h16)1.0f, (h16)1.0f};
    #pragma unroll
    for (int i = 0; i < 4; ++i)
        acc = __builtin_amdgcn_fdot2(
            __builtin_elementwise_max(uq.h[i] - uk.h[i], z), one, acc, false);
#else
    #pragma unroll
    for (int i = 0; i < 4; ++i) {
        v2h d = __builtin_elementwise_max(uq.h[i] - uk.h[i], z);
        acc += (float)d.x + (float)d.y;
    }
#endif
    return acc;
}

// ---------------------------------------------------------------------------
// Kernel T: transpose the three 128x128 W matrices -> Wt[p][d][f].
// ---------------------------------------------------------------------------
__global__ __launch_bounds__(256) void wt_kernel(
    const float* __restrict__ Wq, const float* __restrict__ Wk,
    const float* __restrict__ Wv, float* __restrict__ Wt)
{
    __shared__ float lt[32 * 129];
    const int p = blockIdx.x >> 2;
    const int f0 = (blockIdx.x & 3) * 32;
    const float* W = (p == 0) ? Wq : (p == 1) ? Wk : Wv;
    const int t = threadIdx.x;

    #pragma unroll
    for (int i = 0; i < 16; ++i) {          // load stripe [32f][128d]
        const int n = i * 256 + t;
        const int fi = n >> 7, d = n & 127;
        lt[fi * 129 + d] = W[(f0 + fi) * 128 + d];
    }
    __syncthreads();
    #pragma unroll
    for (int i = 0; i < 16; ++i) {          // store [128d][32f]
        const int m = i * 256 + t;
        const int d = m >> 5, fo = m & 31;
        Wt[p * 16384 + d * 128 + f0 + fo] = lt[fo * 129 + d];
    }
}

// ---------------------------------------------------------------------------
// Kernel A: QKV projection using pre-transposed W (d-major). Grid 768.
// Coalesced W reads (L1-resident), x via LDS broadcast, no in-loop barriers.
// Q,K,V all stored f16.
// ---------------------------------------------------------------------------
__global__ __launch_bounds__(256, 4) void qkv_kernel(
    const float* __restrict__ x, const float* __restrict__ Wt,
    const float* __restrict__ bq, const float* __restrict__ bk,
    const float* __restrict__ bv,
    h16* __restrict__ Qh, h16* __restrict__ Kh, h16* __restrict__ V16)
{
    __shared__ float xs[8 * 128];          // 4 KB
    const int b = blockIdx.x;
    const int p = b >> 8;                  // proj (block-uniform)
    const int row0 = (b & 255) * 8;
    const int t = threadIdx.x;
    const int f = t & 127;
    const int h = t >> 7;                  // rows h*4 .. h*4+3

    ((float4*)xs)[t] = ((const float4*)(x + row0 * DD))[t];
    __syncthreads();

    const float* wt = Wt + p * 16384;
    float acc[4] = {0.f, 0.f, 0.f, 0.f};

    for (int d0 = 0; d0 < 128; d0 += 8) {
        float w[8];
        #pragma unroll
        for (int j = 0; j < 8; ++j) w[j] = wt[(d0 + j) * 128 + f];
        #pragma unroll
        for (int j = 0; j < 8; ++j) {
            #pragma unroll
            for (int r = 0; r < 4; ++r)
                acc[r] += w[j] * xs[(h * 4 + r) * 128 + d0 + j];  // broadcast
        }
    }

    const float bb_ = ((p == 0) ? bq : (p == 1) ? bk : bv)[f];
    #pragma unroll
    for (int r = 0; r < 4; ++r) {
        const int row = row0 + h * 4 + r;
        const float vv = acc[r] + bb_;
        if (p == 0)      Qh[row * DD + f] = (h16)(1.f / (1.f + __expf(-vv)));
        else if (p == 1) Kh[row * DD + f] = (h16)(1.f / (1.f + __expf(-vv)));
        else             V16[row * DD + f] = (h16)vv;
    }
}

// ---------------------------------------------------------------------------
// Kernel S: raw Lukasiewicz scores -> f16 (scores in (0,10], ulp<=0.008).
// Job = (b, qg, k-quarter), grid 2048 (b = job>>10: 0..1). Wave = q row;
// lane = k row in 64-row padded LDS tile (17 float4 stride, conflict-free
// per r7 counters). Causal-inactive quarters return at block granularity;
// lanes with krow > qrow skip the write (pv masks on read).
// ---------------------------------------------------------------------------
__global__ __launch_bounds__(256, 4) void score_kernel(
    const h16* __restrict__ Qh, const h16* __restrict__ Kh,
    const int* __restrict__ causal_flag, h16* __restrict__ scg)
{
    __shared__ float4 Ks4[64 * 17];        // 17.4 KB
    __shared__ float4 qls[64];             // 1 KB

    const int job = blockIdx.x;
    const int kq = job & 3, qg = (job >> 2) & 255, b = job >> 10;
    const int q0 = qg * 4;
    const int kbase = kq * 256;
    const bool causal = (causal_flag[0] != 0);
    if (causal && kbase > q0 + 3) return;  // block-uniform skip
    const int nt = causal ? min(4, ((q0 + 3 - kbase) >> 6) + 1) : 4;

    const int t = threadIdx.x;
    const int q = t >> 6, kk = t & 63;
    const int qrow = q0 + q;

    if (t < 64) qls[t] = ((const float4*)(Qh + (b * SS + q0) * DD))[t];

    const float4* Ksrc = (const float4*)(Kh + (b * SS + kbase) * DD);
    float4 rg[4];
    #pragma unroll
    for (int i = 0; i < 4; ++i) rg[i] = Ksrc[i * 256 + t];   // tile 0

    for (int kt = 0; kt < nt; ++kt) {
        __syncthreads();                   // tile buffer free (+qls, kt=0)
        #pragma unroll
        for (int i = 0; i < 4; ++i) {
            const int n = i * 256 + t, r = n >> 4, s = n & 15;
            Ks4[r * 17 + s] = rg[i];
        }
        __syncthreads();                   // tile visible
        if (kt + 1 < nt) {                 // issue next prefetch
            const float4* src = Ksrc + (kt + 1) * 1024;
            #pragma unroll
            for (int i = 0; i < 4; ++i) rg[i] = src[i * 256 + t];
        }

        float a = 0.f;
        #pragma unroll
        for (int s = 0; s < 16; ++s)
            a = acc8(a, qls[q * 16 + s], Ks4[kk * 17 + s]);

        const int krow = kbase + kt * 64 + kk;
        if (!causal || krow <= qrow)
            scg[(b * SS + qrow) * SS + krow] =
                (h16)((1.f - a * (1.f / DD)) * 10.f);
    }
}

// ---------------------------------------------------------------------------
// Kernel PV: masked-to-0 softmax + PV. Job = (b, qg, d-half), GRID 1024
// (b = job>>9: 0..1 — r9/r11 crash was launching this with grid 2048, which
// decoded b=2,3 and stored past the 1 MB output buffer -> device fault).
// Wave = q row for softmax (16 f16 scores/lane, shfl reduce; causal mask on
// read -> masked entries participate with score 0.0, per ref).
// PV: lane = (kcw 3b | d8 3b); kc = wv*8+kcw owns 32 k rows; k walk staggered
// by kcw*4 so the 8 concurrent LDS broadcasts hit 8 distinct banks.
// ---------------------------------------------------------------------------
__global__ __launch_bounds__(256, 4) void pv_kernel(
    const h16* __restrict__ scg, const h16* __restrict__ V16,
    const int* __restrict__ causal_flag, float* __restrict__ out)
{
    __shared__ float wl[4 * SS];           // 16 KB weights
    __shared__ float pvs[4][4][64];        // 4 KB partials

    const int job = blockIdx.x;
    const int dh = job & 1, qg = (job >> 1) & 255, b = job >> 9;
    const int q0 = qg * 4;
    const bool causal = (causal_flag[0] != 0);
    const int t = threadIdx.x;
    const int wv = t >> 6, lane = t & 63;
    const int qrow = q0 + wv;

    // ---- softmax over row qrow (16 scores/lane) ----
    const h16* srow = scg + (b * SS + qrow) * SS;   // 1024 h16 = 128 float4
    float sv[16];
    #pragma unroll
    for (int j = 0; j < 2; ++j) {
        const float4 raw = ((const float4*)srow)[j * 64 + lane];
        union { float4 f; v2h h[4]; } us; us.f = raw;
        #pragma unroll
        for (int e = 0; e < 4; ++e) {
            const int kb_ = (j * 64 + lane) * 8 + 2 * e;
            float a0 = (float)us.h[e].x, a1 = (float)us.h[e].y;
            if (causal) {                  // mask k>qrow -> 0.0 (participates)
                if (kb_ + 0 > qrow) a0 = 0.f;
                if (kb_ + 1 > qrow) a1 = 0.f;
            }
            sv[j * 8 + 2 * e] = a0;
            sv[j * 8 + 2 * e + 1] = a1;
        }
    }
    float mx = -1e30f;
    #pragma unroll
    for (int i = 0; i < 16; ++i) mx = fmaxf(mx, sv[i]);
    #pragma unroll
    for (int o = 32; o > 0; o >>= 1) mx = fmaxf(mx, __shfl_xor(mx, o));
    float sum = 0.f;
    #pragma unroll
    for (int i = 0; i < 16; ++i) { sv[i] = __expf(sv[i] - mx); sum += sv[i]; }
    #pragma unroll
    for (int o = 32; o > 0; o >>= 1) sum += __shfl_xor(sum, o);
    const float inv = 1.f / sum;

    float4* wrow = (float4*)&wl[wv * SS];
    #pragma unroll
    for (int j = 0; j < 2; ++j) {
        #pragma unroll
        for (int hh = 0; hh < 2; ++hh) {
            float4 o4;
            o4.x = sv[j * 8 + hh * 4 + 0] * inv;
            o4.y = sv[j * 8 + hh * 4 + 1] * inv;
            o4.z = sv[j * 8 + hh * 4 + 2] * inv;
            o4.w = sv[j * 8 + hh * 4 + 3] * inv;
            wrow[(j * 64 + lane) * 2 + hh] = o4;
        }
    }
    __syncthreads();                       // weights visible

    // ---- PV ----
    const int d8 = t & 7, kcw = (t >> 3) & 7, kc = wv * 8 + kcw;
    float acc[4][8];
    #pragma unroll
    for (int qi = 0; qi < 4; ++qi)
        #pragma unroll
        for (int e = 0; e < 8; ++e) acc[qi][e] = 0.f;

    const h16* vbase = V16 + b * SS * DD + dh * 64 + d8 * 8;
    for (int ki = 0; ki < 32; ++ki) {
        const int ki2 = (ki + kcw * 4) & 31;          // bank stagger
        const int k = kc * 32 + ki2;
        const float4 vp = *(const float4*)(vbase + k * DD);
        union { float4 f; v2h h[4]; } uv; uv.f = vp;
        float vf[8];
        #pragma unroll
        for (int e = 0; e < 4; ++e) {
            vf[2 * e]     = (float)uv.h[e].x;
            vf[2 * e + 1] = (float)uv.h[e].y;
        }
        #pragma unroll
        for (int qi = 0; qi < 4; ++qi) {
            const float wq = wl[qi * SS + k];         // 8-bank broadcast
            #pragma unroll
            for (int e = 0; e < 8; ++e) acc[qi][e] += wq * vf[e];
        }
    }
    // reduce over kcw (lane bits 3..5)
    #pragma unroll
    for (int o = 8; o < 64; o <<= 1)
        #pragma unroll
        for (int qi = 0; qi < 4; ++qi)
            #pragma unroll
            for (int e = 0; e < 8; ++e)
                acc[qi][e] += __shfl_xor(acc[qi][e], o);
    if (kcw == 0)
        #pragma unroll
        for (int qi = 0; qi < 4; ++qi)
            #pragma unroll
            for (int e = 0; e < 8; ++e)
                pvs[wv][qi][d8 * 8 + e] = acc[qi][e];
    __syncthreads();                       // partials visible

    {   // final reduce over the 4 waves' k ranges; coalesced store
        const int qi = t >> 6, d = t & 63;
        const float ssum = pvs[0][qi][d] + pvs[1][qi][d]
                         + pvs[2][qi][d] + pvs[3][qi][d];
        out[(b * SS + q0 + qi) * DD + dh * 64 + d] = ssum;
    }
}

extern "C" void kernel_launch(void* const* d_in, const int* in_sizes, int n_in,
                              void* d_out, int out_size, void* d_ws, size_t ws_size,
                              hipStream_t stream) {
    const float* x  = (const float*)d_in[0];
    const float* Wq = (const float*)d_in[1];
    const float* bq = (const float*)d_in[2];
    const float* Wk = (const float*)d_in[3];
    const float* bk = (const float*)d_in[4];
    const float* Wv = (const float*)d_in[5];
    const float* bv = (const float*)d_in[6];
    const int* causal = (const int*)d_in[7];
    float* out = (float*)d_out;

    const int rows = BB * SS;                     // 2048
    float* Wt  = (float*)d_ws;                    // 192 KB
    h16*   Qh  = (h16*)(Wt + 3 * 16384);          // 512 KB
    h16*   Kh  = Qh + rows * DD;                  // 512 KB
    h16*   V16 = Kh + rows * DD;                  // 512 KB
    h16*   scg = V16 + rows * DD;                 // 4 MB f16 raw scores

    wt_kernel<<<12, 256, 0, stream>>>(Wq, Wk, Wv, Wt);
    qkv_kernel<<<768, 256, 0, stream>>>(x, Wt, bq, bk, bv, Qh, Kh, V16);
    score_kernel<<<2048, 256, 0, stream>>>(Qh, Kh, causal, scg);
    pv_kernel<<<1024, 256, 0, stream>>>(scg, V16, causal, out);   // 1024 jobs!
}